// Round 7
// baseline (771.887 us; speedup 1.0000x reference)
//
#include <hip/hip_runtime.h>
#include <hip/hip_cooperative_groups.h>

namespace cg = cooperative_groups;

#define TPB 256
#define CGRID 256      // cooperative grid: 1 block per CU
#define CTPB 1024      // 16 waves per block
#define KB_BITS 8      // 256 items per bucket
#define MAXB 6144      // bucket cap (mean ~4080, sigma ~64 -> +32 sigma)

// ---- bf16 pack/unpack helpers (RNE) ----
__device__ __forceinline__ unsigned int bf16pair(float a, float b) {
  unsigned int ua = __float_as_uint(a);
  ua += 0x7fffu + ((ua >> 16) & 1u);
  unsigned int ub = __float_as_uint(b);
  ub += 0x7fffu + ((ub >> 16) & 1u);
  return (ua >> 16) | (ub & 0xffff0000u);
}
__device__ __forceinline__ float bf16lo(unsigned int u) { return __uint_as_float(u << 16); }
__device__ __forceinline__ float bf16hi(unsigned int u) { return __uint_as_float(u & 0xffff0000u); }

// ---- non-temporal (evict-first) vector load/store helpers ----
typedef unsigned int u32x4v __attribute__((ext_vector_type(4)));
typedef float f32x4v __attribute__((ext_vector_type(4)));

__device__ __forceinline__ uint4 ntload_u4(const uint4* p) {
  u32x4v v = __builtin_nontemporal_load(reinterpret_cast<const u32x4v*>(p));
  return make_uint4(v.x, v.y, v.z, v.w);
}
__device__ __forceinline__ float4 ntload_f4(const float4* p) {
  f32x4v v = __builtin_nontemporal_load(reinterpret_cast<const f32x4v*>(p));
  return make_float4(v.x, v.y, v.z, v.w);
}
__device__ __forceinline__ void ntstore_u4(uint4* p, uint4 v) {
  u32x4v t; t.x = v.x; t.y = v.y; t.z = v.z; t.w = v.w;
  __builtin_nontemporal_store(t, reinterpret_cast<u32x4v*>(p));
}
__device__ __forceinline__ void ntstore_f4(float4* p, float4 v) {
  f32x4v t; t.x = v.x; t.y = v.y; t.z = v.z; t.w = v.w;
  __builtin_nontemporal_store(t, reinterpret_cast<f32x4v*>(p));
}

// wave64 inclusive scan (shuffle ladder, no barriers)
__device__ __forceinline__ int wave_incl_scan(int v, int lane) {
#pragma unroll
  for (int d = 1; d < 64; d <<= 1) {
    int t = __shfl_up(v, d, 64);
    if (lane >= d) v += t;
  }
  return v;
}

// Fused cooperative CSR build + x0 init. All phases are the R6-verified
// kernels with kernel boundaries replaced by grid.sync() (each boundary was a
// full-device drain+ramp bubble; useful CSR work is only ~50us). 256 blocks x
// 1024 threads = 1 block/CU, ~30KB LDS -> co-residency guaranteed.
// No global atomics anywhere (R4 lesson: cross-XCD atomic RMW ~68ns each).
__global__ __launch_bounds__(CTPB) void csr_fused(
    const int* __restrict__ row, const int* __restrict__ col,
    const float* __restrict__ uemb, const float* __restrict__ iemb,
    int* __restrict__ rp, int* __restrict__ wgcnt, int* __restrict__ btot,
    int* __restrict__ rpB, unsigned int* __restrict__ evcol,
    uint2* __restrict__ x0,
    int Eh, int E, int NU, int NI, int N, int K, int chunk, int NU16, int N16) {
  cg::grid_group grid = cg::this_grid();
  __shared__ int sh[1024];            // bucket hist (A2) / partition cursors (D)
  __shared__ unsigned int lcol[MAXB]; // bucket edge staging (E)
  __shared__ int bins[256];
  __shared__ int wsum[16];
  const int b0 = blockIdx.x, t = threadIdx.x;
  const int lane = t & 63, wv = t >> 6;

  // --- Phase A1: user-row rp from run-length boundaries (row[0..Eh) sorted) ---
  for (int e = b0 * CTPB + t; e < Eh; e += CGRID * CTPB) {
    int r = row[e];
    int rprev = (e == 0) ? -1 : row[e - 1];
    for (int rr = rprev + 1; rr <= r; ++rr) rp[rr] = e;
    if (e == Eh - 1) {
      for (int rr = r + 1; rr < NU; ++rr) rp[rr] = Eh;
    }
  }
  // --- Phase A2: per-block item-bucket histogram (LDS atomics) ---
  for (int i = t; i < K; i += CTPB) sh[i] = 0;
  __syncthreads();
  const int s0 = Eh + b0 * chunk;
  const int e1 = (s0 + chunk < E) ? s0 + chunk : E;
  for (int e = s0 + t; e < e1; e += CTPB)
    atomicAdd(&sh[(row[e] - NU) >> KB_BITS], 1);
  __syncthreads();
  for (int i = t; i < K; i += CTPB) wgcnt[i * CGRID + b0] = sh[i];
  grid.sync();

  // --- Phase B: per-bucket exclusive scan over CGRID wg counts ---
  for (int b = b0; b < K; b += CGRID) {
    int v = 0, s = 0;
    if (t < CGRID) {
      v = wgcnt[b * CGRID + t];
      s = wave_incl_scan(v, lane);
      if (lane == 63) wsum[wv] = s;
    }
    __syncthreads();
    if (t < CGRID) {
      int base = 0;
#pragma unroll
      for (int w = 0; w < CGRID / 64; ++w)
        if (w < wv) base += wsum[w];
      wgcnt[b * CGRID + t] = base + s - v;  // exclusive
      if (t == CGRID - 1) btot[b] = base + s;
    }
    __syncthreads();
  }
  grid.sync();

  // --- Phase C: block 0 scans bucket totals -> rpB (base Eh) ---
  if (b0 == 0) {
    int v = (t < K) ? btot[t] : 0;
    int s = wave_incl_scan(v, lane);
    if (lane == 63) wsum[wv] = s;
    __syncthreads();
    int base = Eh;
    for (int w = 0; w < 16; ++w)
      if (w < wv) base += wsum[w];
    if (t < K) rpB[t] = base + s - v;
    if (t == 0) { rpB[K] = E; rp[N] = E; }
  }
  grid.sync();

  // --- Phase D: partition second-half edges into bucket regions (packed) ---
  for (int i = t; i < K; i += CTPB) sh[i] = rpB[i] + wgcnt[i * CGRID + b0];
  __syncthreads();
  for (int e = s0 + t; e < e1; e += CTPB) {
    int li = row[e] - NU;
    int b = li >> KB_BITS;
    int p = atomicAdd(&sh[b], 1);
    evcol[p] = ((unsigned int)(li & 255) << 24) | (unsigned int)col[e];
  }
  grid.sync();

  // --- Phase E: in-LDS counting sort per bucket; emits item rp, unpacks evcol ---
  for (int b = b0; b < K; b += CGRID) {
    int start = rpB[b], end = rpB[b + 1];
    int nb = end - start;
    if (t < 256) bins[t] = 0;
    __syncthreads();
    for (int i = t; i < nb; i += CTPB) {
      unsigned int v = evcol[start + i];
      lcol[i] = v;
      atomicAdd(&bins[v >> 24], 1);
    }
    __syncthreads();
    int v2 = 0, s2 = 0;
    if (t < 256) {
      v2 = bins[t];
      s2 = wave_incl_scan(v2, lane);
      if (lane == 63) wsum[wv] = s2;
    }
    __syncthreads();
    if (t < 256) {
      int base = 0;
#pragma unroll
      for (int w = 0; w < 4; ++w)
        if (w < wv) base += wsum[w];
      int excl = base + s2 - v2;
      int item = (b << KB_BITS) + t;
      if (item < NI) rp[NU + item] = start + excl;
      bins[t] = excl;  // reuse as fill cursors
    }
    __syncthreads();
    for (int i = t; i < nb; i += CTPB) {
      unsigned int pk = lcol[i];
      int p = atomicAdd(&bins[pk >> 24], 1);
      evcol[start + p] = pk & 0xFFFFFFu;
    }
    __syncthreads();
  }
  grid.sync();

  // --- Phase F: x0(bf16)[i] = rsqrt(deg+1e-7) * concat(uemb, iemb) ---
  for (int i = b0 * CTPB + t; i < N16; i += CGRID * CTPB) {
    float4 v = (i < NU16) ? ntload_f4(reinterpret_cast<const float4*>(uemb) + i)
                          : ntload_f4(reinterpret_cast<const float4*>(iemb) + (i - NU16));
    int r = i >> 4;
    float deg = (float)(rp[r + 1] - rp[r]) + 1e-7f;
    float dv = rsqrtf(deg);
    x0[i] = make_uint2(bf16pair(dv * v.x, dv * v.y), bf16pair(dv * v.z, dv * v.w));
  }
}

// Shared gather body: 8-lane group per destination row; lane l holds dims
// [8l,8l+8); x4 unroll, 28-VGPR proven config. Gather is at the cross-XCD
// compulsory-fetch floor (R3 audit, service-rate model closes within 4%) --
// do not touch.
__device__ __forceinline__ void gather_row(const uint4* __restrict__ xv4,
                                           const unsigned int* __restrict__ ec,
                                           int start, int end, int l, float* a) {
#pragma unroll
  for (int k = 0; k < 8; ++k) a[k] = 0.f;
  int j = start;
  for (; j + 3 < end; j += 4) {
    unsigned int c0 = ec[j], c1 = ec[j + 1], c2 = ec[j + 2], c3 = ec[j + 3];
    uint4 p0 = xv4[(size_t)c0 * 8 + l];
    uint4 p1 = xv4[(size_t)c1 * 8 + l];
    uint4 p2 = xv4[(size_t)c2 * 8 + l];
    uint4 p3 = xv4[(size_t)c3 * 8 + l];
    a[0] += bf16lo(p0.x); a[1] += bf16hi(p0.x); a[2] += bf16lo(p0.y); a[3] += bf16hi(p0.y);
    a[4] += bf16lo(p0.z); a[5] += bf16hi(p0.z); a[6] += bf16lo(p0.w); a[7] += bf16hi(p0.w);
    a[0] += bf16lo(p1.x); a[1] += bf16hi(p1.x); a[2] += bf16lo(p1.y); a[3] += bf16hi(p1.y);
    a[4] += bf16lo(p1.z); a[5] += bf16hi(p1.z); a[6] += bf16lo(p1.w); a[7] += bf16hi(p1.w);
    a[0] += bf16lo(p2.x); a[1] += bf16hi(p2.x); a[2] += bf16lo(p2.y); a[3] += bf16hi(p2.y);
    a[4] += bf16lo(p2.z); a[5] += bf16hi(p2.z); a[6] += bf16lo(p2.w); a[7] += bf16hi(p2.w);
    a[0] += bf16lo(p3.x); a[1] += bf16hi(p3.x); a[2] += bf16lo(p3.y); a[3] += bf16hi(p3.y);
    a[4] += bf16lo(p3.z); a[5] += bf16hi(p3.z); a[6] += bf16lo(p3.w); a[7] += bf16hi(p3.w);
  }
  for (; j < end; ++j) {
    unsigned int c0 = ec[j];
    uint4 p = xv4[(size_t)c0 * 8 + l];
    a[0] += bf16lo(p.x); a[1] += bf16hi(p.x); a[2] += bf16lo(p.y); a[3] += bf16hi(p.y);
    a[4] += bf16lo(p.z); a[5] += bf16hi(p.z); a[6] += bf16lo(p.w); a[7] += bf16hi(p.w);
  }
}

// Layers 1,2: x~next = bf16(s/(deg+eps)). User rows read input `col` directly.
__global__ void spmm_kernel(const unsigned int* __restrict__ x, unsigned int* __restrict__ y,
                            const int* __restrict__ rp,
                            const unsigned int* __restrict__ col_u,
                            const unsigned int* __restrict__ evcol, int N, int NU) {
  int t = blockIdx.x * TPB + threadIdx.x;
  int g = t >> 3;
  int l = t & 7;
  if (g >= N) return;
  int start = rp[g], end = rp[g + 1];
  const unsigned int* ec = (g < NU) ? col_u : evcol;
  float a[8];
  gather_row(reinterpret_cast<const uint4*>(x), ec, start, end, l, a);
  float d2 = 1.0f / ((float)(end - start) + 1e-7f);
  uint4 yo;
  yo.x = bf16pair(d2 * a[0], d2 * a[1]); yo.y = bf16pair(d2 * a[2], d2 * a[3]);
  yo.z = bf16pair(d2 * a[4], d2 * a[5]); yo.w = bf16pair(d2 * a[6], d2 * a[7]);
  ntstore_u4(reinterpret_cast<uint4*>(y) + (size_t)g * 8 + l, yo);
}

// Layer 3 fused with the mean-over-layers combine:
// out[g] = 0.25 * (emb[g] + sqdeg*(x~1[g]+x~2[g]) + dinv*s),  s = sum x~2[c].
__global__ void spmm_last_kernel(const unsigned int* __restrict__ x,
                                 const int* __restrict__ rp,
                                 const unsigned int* __restrict__ col_u,
                                 const unsigned int* __restrict__ evcol,
                                 const unsigned int* __restrict__ x1,
                                 const unsigned int* __restrict__ x2,
                                 const float* __restrict__ uemb,
                                 const float* __restrict__ iemb,
                                 float* __restrict__ out, int N, int NU) {
  int t = blockIdx.x * TPB + threadIdx.x;
  int g = t >> 3;
  int l = t & 7;
  if (g >= N) return;
  int start = rp[g], end = rp[g + 1];
  const unsigned int* ec = (g < NU) ? col_u : evcol;
  float a[8];
  gather_row(reinterpret_cast<const uint4*>(x), ec, start, end, l, a);
  float deg = (float)(end - start) + 1e-7f;
  float dinv = rsqrtf(deg);
  float sq = deg * dinv;  // sqrt(deg+eps)
  uint4 p1 = ntload_u4(reinterpret_cast<const uint4*>(x1) + (size_t)g * 8 + l);
  uint4 p2 = reinterpret_cast<const uint4*>(x2)[(size_t)g * 8 + l];
  const float4* ep = (g < NU)
      ? reinterpret_cast<const float4*>(uemb) + (size_t)g * 16
      : reinterpret_cast<const float4*>(iemb) + (size_t)(g - NU) * 16;
  float4 e0 = ntload_f4(ep + 2 * l), e1 = ntload_f4(ep + 2 * l + 1);
  float t0 = bf16lo(p1.x) + bf16lo(p2.x), t1 = bf16hi(p1.x) + bf16hi(p2.x);
  float t2 = bf16lo(p1.y) + bf16lo(p2.y), t3 = bf16hi(p1.y) + bf16hi(p2.y);
  float t4 = bf16lo(p1.z) + bf16lo(p2.z), t5 = bf16hi(p1.z) + bf16hi(p2.z);
  float t6 = bf16lo(p1.w) + bf16lo(p2.w), t7 = bf16hi(p1.w) + bf16hi(p2.w);
  float4 o0, o1;
  o0.x = 0.25f * (e0.x + sq * t0 + dinv * a[0]);
  o0.y = 0.25f * (e0.y + sq * t1 + dinv * a[1]);
  o0.z = 0.25f * (e0.z + sq * t2 + dinv * a[2]);
  o0.w = 0.25f * (e0.w + sq * t3 + dinv * a[3]);
  o1.x = 0.25f * (e1.x + sq * t4 + dinv * a[4]);
  o1.y = 0.25f * (e1.y + sq * t5 + dinv * a[5]);
  o1.z = 0.25f * (e1.z + sq * t6 + dinv * a[6]);
  o1.w = 0.25f * (e1.w + sq * t7 + dinv * a[7]);
  float4* op = reinterpret_cast<float4*>(out) + (size_t)g * 16;
  ntstore_f4(op + 2 * l, o0);
  ntstore_f4(op + 2 * l + 1, o1);
}

static inline char* align256(char* p) {
  return (char*)(((uintptr_t)p + 255) & ~(uintptr_t)255);
}

extern "C" void kernel_launch(void* const* d_in, const int* in_sizes, int n_in,
                              void* d_out, int out_size, void* d_ws, size_t ws_size,
                              hipStream_t stream) {
  const int* row = (const int*)d_in[2];
  const int* col = (const int*)d_in[3];
  const float* user_emb = (const float*)d_in[0];
  const float* item_emb = (const float*)d_in[1];
  // vals (d_in[4]) recomputed from degrees.

  const int NU = in_sizes[0] / 64;
  const int NI = in_sizes[1] / 64;
  const int N = NU + NI;
  const int E = in_sizes[2];
  const int Eh = E / 2;          // first half = user rows, already CSR-sorted
  const int Eh2 = E - Eh;

  float* out = (float*)d_out;

  const int K = (NI + 255) >> KB_BITS;  // item buckets of 256 (<=1024 fits sh[])

  // workspace carve-up (256B-aligned blocks); 3 bf16 x-buffers kept live.
  char* p = (char*)d_ws;
  unsigned int* xb[3];
  for (int k = 0; k < 3; ++k) { xb[k] = (unsigned int*)p; p = align256(p + (size_t)N * 64 * 2); }
  int* rp = (int*)p;                   p = align256(p + (size_t)(N + 1) * 4);
  int* wgcnt = (int*)p;                p = align256(p + (size_t)K * CGRID * 4);
  int* btot = (int*)p;                 p = align256(p + (size_t)K * 4);
  int* rpB = (int*)p;                  p = align256(p + (size_t)(K + 1) * 4);
  unsigned int* evcol = (unsigned int*)p;  // E * 4 bytes (only [Eh,E) used)

  const int N16 = N * 16;
  const int NU16 = NU * 16;
  const int chunk = (Eh2 + CGRID - 1) / CGRID;

  // --- fused CSR build + x0 init: one cooperative kernel, 6 phases ---
  {
    uint2* x0 = (uint2*)xb[0];
    int Eh_ = Eh, E_ = E, NU_ = NU, NI_ = NI, N_ = N, K_ = K, chunk_ = chunk,
        NU16_ = NU16, N16_ = N16;
    const int* row_ = row; const int* col_ = col;
    const float* ue_ = user_emb; const float* ie_ = item_emb;
    int* rp_ = rp; int* wg_ = wgcnt; int* bt_ = btot; int* rb_ = rpB;
    unsigned int* ev_ = evcol;
    void* args[] = {&row_, &col_, &ue_, &ie_, &rp_, &wg_, &bt_, &rb_, &ev_, &x0,
                    &Eh_, &E_, &NU_, &NI_, &N_, &K_, &chunk_, &NU16_, &N16_};
    hipLaunchCooperativeKernel((const void*)csr_fused, dim3(CGRID), dim3(CTPB),
                               args, 0, stream);
  }

  // --- propagation: layers 1,2 write x~; layer 3 fused with combine ---
  const int spmm_blocks = (N * 8 + TPB - 1) / TPB;
  spmm_kernel<<<spmm_blocks, TPB, 0, stream>>>(xb[0], xb[1], rp,
                                               (const unsigned int*)col, evcol, N, NU);
  spmm_kernel<<<spmm_blocks, TPB, 0, stream>>>(xb[1], xb[2], rp,
                                               (const unsigned int*)col, evcol, N, NU);
  spmm_last_kernel<<<spmm_blocks, TPB, 0, stream>>>(xb[2], rp,
                                                    (const unsigned int*)col, evcol,
                                                    xb[1], xb[2], user_emb, item_emb,
                                                    out, N, NU);
}

// Round 8
// 589.794 us; speedup vs baseline: 1.3087x; 1.3087x over previous
//
#include <hip/hip_runtime.h>

#define TPB 256
#define BPB 1024       // big blocks for K1-hist/P3: 16 waves per wg, 1 wg/CU
#define NWG 256        // partition chunks: run length ~16 edges = one full 64B sector
#define KB_BITS 8      // 256 items per bucket
#define MAXB 6144      // bucket cap (mean 4003, sigma 63 -> +34 sigma), ~26KB LDS -> 6 wgs/CU

// ---- bf16 pack/unpack helpers (RNE) ----
__device__ __forceinline__ unsigned int bf16pair(float a, float b) {
  unsigned int ua = __float_as_uint(a);
  ua += 0x7fffu + ((ua >> 16) & 1u);
  unsigned int ub = __float_as_uint(b);
  ub += 0x7fffu + ((ub >> 16) & 1u);
  return (ua >> 16) | (ub & 0xffff0000u);
}
__device__ __forceinline__ float bf16lo(unsigned int u) { return __uint_as_float(u << 16); }
__device__ __forceinline__ float bf16hi(unsigned int u) { return __uint_as_float(u & 0xffff0000u); }

// ---- non-temporal (evict-first) vector load/store helpers (R3: ~neutral, kept) ----
typedef unsigned int u32x4v __attribute__((ext_vector_type(4)));
typedef float f32x4v __attribute__((ext_vector_type(4)));

__device__ __forceinline__ uint4 ntload_u4(const uint4* p) {
  u32x4v v = __builtin_nontemporal_load(reinterpret_cast<const u32x4v*>(p));
  return make_uint4(v.x, v.y, v.z, v.w);
}
__device__ __forceinline__ float4 ntload_f4(const float4* p) {
  f32x4v v = __builtin_nontemporal_load(reinterpret_cast<const f32x4v*>(p));
  return make_float4(v.x, v.y, v.z, v.w);
}
__device__ __forceinline__ void ntstore_u4(uint4* p, uint4 v) {
  u32x4v t; t.x = v.x; t.y = v.y; t.z = v.z; t.w = v.w;
  __builtin_nontemporal_store(t, reinterpret_cast<u32x4v*>(p));
}
__device__ __forceinline__ void ntstore_f4(float4* p, float4 v) {
  f32x4v t; t.x = v.x; t.y = v.y; t.z = v.z; t.w = v.w;
  __builtin_nontemporal_store(t, reinterpret_cast<f32x4v*>(p));
}

// wave64 inclusive scan (shuffle ladder, no barriers)
__device__ __forceinline__ int wave_incl_scan(int v, int lane) {
#pragma unroll
  for (int d = 1; d < 64; d <<= 1) {
    int t = __shfl_up(v, d, 64);
    if (lane >= d) v += t;
  }
  return v;
}

// K1 fused: blocks [0,BU) build user-row rp by run-length boundaries (first
// half of `row` is sorted ascending); blocks [BU,BU+NWG) histogram item
// buckets with LDS atomics only (R4 lesson: global atomics = ~68ns RMWs;
// R7 lesson: cooperative single-launch fusion serializes to 16 waves/CU and
// LOSES 180us -- keep separate kernels at full occupancy).
__global__ __launch_bounds__(BPB) void rp_user_and_hist(
    const int* __restrict__ row, int* __restrict__ rp, int* __restrict__ wgcnt,
    int Eh, int E, int NU, int K, int chunk, int BU) {
  extern __shared__ int hist[];
  if ((int)blockIdx.x < BU) {
    int e = blockIdx.x * BPB + threadIdx.x;
    if (e >= Eh) return;
    int r = row[e];
    int rprev = (e == 0) ? -1 : row[e - 1];
    for (int rr = rprev + 1; rr <= r; ++rr) rp[rr] = e;
    if (e == Eh - 1) {
      for (int rr = r + 1; rr < NU; ++rr) rp[rr] = Eh;
    }
  } else {
    int w = blockIdx.x - BU, tid = threadIdx.x;
    for (int b = tid; b < K; b += BPB) hist[b] = 0;
    __syncthreads();
    int s = Eh + w * chunk;
    int e_end = s + chunk; if (e_end > E) e_end = E;
    for (int e = s + tid; e < e_end; e += BPB)
      atomicAdd(&hist[(row[e] - NU) >> KB_BITS], 1);
    __syncthreads();
    for (int b = tid; b < K; b += BPB) wgcnt[b * NWG + w] = hist[b];
  }
}

// P2a: per-bucket exclusive scan over NWG wg-counts via wave scans; totals out.
__global__ __launch_bounds__(TPB) void p2a_scan(int* __restrict__ wgcnt,
                                                int* __restrict__ btot) {
  __shared__ int wsum[4];
  int b = blockIdx.x, t = threadIdx.x;
  int lane = t & 63, wv = t >> 6;
  int v = wgcnt[b * NWG + t];  // NWG == TPB
  int s = wave_incl_scan(v, lane);
  if (lane == 63) wsum[wv] = s;
  __syncthreads();
  int base = 0;
#pragma unroll
  for (int w = 0; w < 4; ++w)
    if (w < wv) base += wsum[w];
  wgcnt[b * NWG + t] = base + s - v;  // exclusive
  if (t == TPB - 1) btot[b] = base + s;
}

// P2b: single-block exclusive scan of K (<=1024) bucket totals -> rpB (base Eh).
__global__ __launch_bounds__(BPB) void p2b_scan(const int* __restrict__ btot,
                                                int* __restrict__ rpB,
                                                int* __restrict__ rp,
                                                int K, int Eh, int E, int N) {
  __shared__ int wsum[16];
  int t = threadIdx.x, lane = t & 63, wv = t >> 6;
  int v = (t < K) ? btot[t] : 0;
  int s = wave_incl_scan(v, lane);
  if (lane == 63) wsum[wv] = s;
  __syncthreads();
  int base = Eh;
  for (int w = 0; w < 16; ++w)
    if (w < wv) base += wsum[w];
  if (t < K) rpB[t] = base + s - v;
  if (t == 0) { rpB[K] = E; rp[N] = E; }
}

// P3: partition second-half edges into bucket-contiguous regions of evcol.
// Packs (item & 255) << 24 | u. BPB threads x NWG wgs: 16 waves/CU for latency
// hiding AND 16-entry runs (one wg assembles each 64B sector).
__global__ __launch_bounds__(BPB) void p3_part(
    const int* __restrict__ row, const int* __restrict__ col,
    const int* __restrict__ wgcnt, const int* __restrict__ rpB,
    unsigned int* __restrict__ evcol, int Eh, int E, int NU, int K, int chunk) {
  extern __shared__ int pos[];
  int w = blockIdx.x, tid = threadIdx.x;
  for (int b = tid; b < K; b += BPB) pos[b] = rpB[b] + wgcnt[b * NWG + w];
  __syncthreads();
  int s = Eh + w * chunk;
  int e_end = s + chunk; if (e_end > E) e_end = E;
  for (int e = s + tid; e < e_end; e += BPB) {
    int li = row[e] - NU;
    int b = li >> KB_BITS;
    int p = atomicAdd(&pos[b], 1);
    evcol[p] = ((unsigned int)(li & 255) << 24) | (unsigned int)col[e];
  }
}

// P4: in-LDS counting sort of each bucket by item low-byte; emits item rp,
// unpacks evcol, AND initializes the item rows of x0 (degree = this block's
// per-item count, already in registers; coalesced float4/uint2 tail loop).
// Folding item-init here removes a 77MB standalone kernel pass dependency.
__global__ __launch_bounds__(TPB) void p4_sort(unsigned int* __restrict__ evcol,
                                               const int* __restrict__ rpB,
                                               int* __restrict__ rp,
                                               const float* __restrict__ iemb,
                                               uint2* __restrict__ x0,
                                               int NU, int NI) {
  __shared__ unsigned int lcol[MAXB];
  __shared__ int bins[256];
  __shared__ int degs[256];
  __shared__ int wsum[4];
  int b = blockIdx.x, t = threadIdx.x;
  int start = rpB[b], end = rpB[b + 1];
  int nb = end - start;
  bins[t] = 0;
  __syncthreads();
  for (int i = t; i < nb; i += TPB) {
    unsigned int v = evcol[start + i];
    lcol[i] = v;
    atomicAdd(&bins[v >> 24], 1);
  }
  __syncthreads();
  int v = bins[t];
  degs[t] = v;  // per-item degree for the x0-init tail
  int lane = t & 63, wv = t >> 6;
  int s = wave_incl_scan(v, lane);
  if (lane == 63) wsum[wv] = s;
  __syncthreads();
  int base = 0;
#pragma unroll
  for (int w = 0; w < 4; ++w)
    if (w < wv) base += wsum[w];
  int excl = base + s - v;
  int item0 = (b << KB_BITS) + t;
  if (item0 < NI) rp[NU + item0] = start + excl;
  bins[t] = excl;  // reuse as fill cursors (local offsets)
  __syncthreads();
  for (int i = t; i < nb; i += TPB) {
    unsigned int pk = lcol[i];
    int p = atomicAdd(&bins[pk >> 24], 1);
    evcol[start + p] = pk & 0xFFFFFFu;
  }
  // --- tail: x0 init for this block's 256 items (degs written pre-barrier) ---
  const float4* if4 = reinterpret_cast<const float4*>(iemb);
  int ibase = b << KB_BITS;
  for (int i2 = t; i2 < 256 * 16; i2 += TPB) {
    int il = i2 >> 4;
    int item = ibase + il;
    if (item >= NI) break;  // il monotone in i2 -> safe per-thread break
    int k = i2 & 15;
    float4 vv = ntload_f4(if4 + (size_t)item * 16 + k);
    float dv = rsqrtf((float)degs[il] + 1e-7f);
    x0[((size_t)(NU + item)) * 16 + k] =
        make_uint2(bf16pair(dv * vv.x, dv * vv.y), bf16pair(dv * vv.z, dv * vv.w));
  }
}

// x0(bf16) init, USER rows only (item rows done in p4_sort's tail).
__global__ void init_scaled(const float* __restrict__ u, const int* __restrict__ rp,
                            uint2* __restrict__ x0, int NU16) {
  int i = blockIdx.x * TPB + threadIdx.x;
  if (i >= NU16) return;
  float4 v = ntload_f4(reinterpret_cast<const float4*>(u) + i);
  int r = i >> 4;
  float deg = (float)(rp[r + 1] - rp[r]) + 1e-7f;
  float dv = rsqrtf(deg);
  x0[i] = make_uint2(bf16pair(dv * v.x, dv * v.y), bf16pair(dv * v.z, dv * v.w));
}

// Shared gather body: 8-lane group per destination row; lane l holds dims
// [8l,8l+8); x4 unroll, 28-VGPR proven config. Gather is at the cross-XCD
// compulsory-fetch floor (R3 audit, service-rate model closes within 4%) --
// do not touch.
__device__ __forceinline__ void gather_row(const uint4* __restrict__ xv4,
                                           const unsigned int* __restrict__ ec,
                                           int start, int end, int l, float* a) {
#pragma unroll
  for (int k = 0; k < 8; ++k) a[k] = 0.f;
  int j = start;
  for (; j + 3 < end; j += 4) {
    unsigned int c0 = ec[j], c1 = ec[j + 1], c2 = ec[j + 2], c3 = ec[j + 3];
    uint4 p0 = xv4[(size_t)c0 * 8 + l];
    uint4 p1 = xv4[(size_t)c1 * 8 + l];
    uint4 p2 = xv4[(size_t)c2 * 8 + l];
    uint4 p3 = xv4[(size_t)c3 * 8 + l];
    a[0] += bf16lo(p0.x); a[1] += bf16hi(p0.x); a[2] += bf16lo(p0.y); a[3] += bf16hi(p0.y);
    a[4] += bf16lo(p0.z); a[5] += bf16hi(p0.z); a[6] += bf16lo(p0.w); a[7] += bf16hi(p0.w);
    a[0] += bf16lo(p1.x); a[1] += bf16hi(p1.x); a[2] += bf16lo(p1.y); a[3] += bf16hi(p1.y);
    a[4] += bf16lo(p1.z); a[5] += bf16hi(p1.z); a[6] += bf16lo(p1.w); a[7] += bf16hi(p1.w);
    a[0] += bf16lo(p2.x); a[1] += bf16hi(p2.x); a[2] += bf16lo(p2.y); a[3] += bf16hi(p2.y);
    a[4] += bf16lo(p2.z); a[5] += bf16hi(p2.z); a[6] += bf16lo(p2.w); a[7] += bf16hi(p2.w);
    a[0] += bf16lo(p3.x); a[1] += bf16hi(p3.x); a[2] += bf16lo(p3.y); a[3] += bf16hi(p3.y);
    a[4] += bf16lo(p3.z); a[5] += bf16hi(p3.z); a[6] += bf16lo(p3.w); a[7] += bf16hi(p3.w);
  }
  for (; j < end; ++j) {
    unsigned int c0 = ec[j];
    uint4 p = xv4[(size_t)c0 * 8 + l];
    a[0] += bf16lo(p.x); a[1] += bf16hi(p.x); a[2] += bf16lo(p.y); a[3] += bf16hi(p.y);
    a[4] += bf16lo(p.z); a[5] += bf16hi(p.z); a[6] += bf16lo(p.w); a[7] += bf16hi(p.w);
  }
}

// Layers 1,2: x~next = bf16(s/(deg+eps)). User rows read input `col` directly.
__global__ void spmm_kernel(const unsigned int* __restrict__ x, unsigned int* __restrict__ y,
                            const int* __restrict__ rp,
                            const unsigned int* __restrict__ col_u,
                            const unsigned int* __restrict__ evcol, int N, int NU) {
  int t = blockIdx.x * TPB + threadIdx.x;
  int g = t >> 3;
  int l = t & 7;
  if (g >= N) return;
  int start = rp[g], end = rp[g + 1];
  const unsigned int* ec = (g < NU) ? col_u : evcol;
  float a[8];
  gather_row(reinterpret_cast<const uint4*>(x), ec, start, end, l, a);
  float d2 = 1.0f / ((float)(end - start) + 1e-7f);
  uint4 yo;
  yo.x = bf16pair(d2 * a[0], d2 * a[1]); yo.y = bf16pair(d2 * a[2], d2 * a[3]);
  yo.z = bf16pair(d2 * a[4], d2 * a[5]); yo.w = bf16pair(d2 * a[6], d2 * a[7]);
  ntstore_u4(reinterpret_cast<uint4*>(y) + (size_t)g * 8 + l, yo);
}

// Layer 3 fused with the mean-over-layers combine:
// out[g] = 0.25 * (emb[g] + sqdeg*(x~1[g]+x~2[g]) + dinv*s),  s = sum x~2[c].
__global__ void spmm_last_kernel(const unsigned int* __restrict__ x,
                                 const int* __restrict__ rp,
                                 const unsigned int* __restrict__ col_u,
                                 const unsigned int* __restrict__ evcol,
                                 const unsigned int* __restrict__ x1,
                                 const unsigned int* __restrict__ x2,
                                 const float* __restrict__ uemb,
                                 const float* __restrict__ iemb,
                                 float* __restrict__ out, int N, int NU) {
  int t = blockIdx.x * TPB + threadIdx.x;
  int g = t >> 3;
  int l = t & 7;
  if (g >= N) return;
  int start = rp[g], end = rp[g + 1];
  const unsigned int* ec = (g < NU) ? col_u : evcol;
  float a[8];
  gather_row(reinterpret_cast<const uint4*>(x), ec, start, end, l, a);
  float deg = (float)(end - start) + 1e-7f;
  float dinv = rsqrtf(deg);
  float sq = deg * dinv;  // sqrt(deg+eps)
  uint4 p1 = ntload_u4(reinterpret_cast<const uint4*>(x1) + (size_t)g * 8 + l);
  uint4 p2 = reinterpret_cast<const uint4*>(x2)[(size_t)g * 8 + l];
  const float4* ep = (g < NU)
      ? reinterpret_cast<const float4*>(uemb) + (size_t)g * 16
      : reinterpret_cast<const float4*>(iemb) + (size_t)(g - NU) * 16;
  float4 e0 = ntload_f4(ep + 2 * l), e1 = ntload_f4(ep + 2 * l + 1);
  float t0 = bf16lo(p1.x) + bf16lo(p2.x), t1 = bf16hi(p1.x) + bf16hi(p2.x);
  float t2 = bf16lo(p1.y) + bf16lo(p2.y), t3 = bf16hi(p1.y) + bf16hi(p2.y);
  float t4 = bf16lo(p1.z) + bf16lo(p2.z), t5 = bf16hi(p1.z) + bf16hi(p2.z);
  float t6 = bf16lo(p1.w) + bf16lo(p2.w), t7 = bf16hi(p1.w) + bf16hi(p2.w);
  float4 o0, o1;
  o0.x = 0.25f * (e0.x + sq * t0 + dinv * a[0]);
  o0.y = 0.25f * (e0.y + sq * t1 + dinv * a[1]);
  o0.z = 0.25f * (e0.z + sq * t2 + dinv * a[2]);
  o0.w = 0.25f * (e0.w + sq * t3 + dinv * a[3]);
  o1.x = 0.25f * (e1.x + sq * t4 + dinv * a[4]);
  o1.y = 0.25f * (e1.y + sq * t5 + dinv * a[5]);
  o1.z = 0.25f * (e1.z + sq * t6 + dinv * a[6]);
  o1.w = 0.25f * (e1.w + sq * t7 + dinv * a[7]);
  float4* op = reinterpret_cast<float4*>(out) + (size_t)g * 16;
  ntstore_f4(op + 2 * l, o0);
  ntstore_f4(op + 2 * l + 1, o1);
}

static inline char* align256(char* p) {
  return (char*)(((uintptr_t)p + 255) & ~(uintptr_t)255);
}

extern "C" void kernel_launch(void* const* d_in, const int* in_sizes, int n_in,
                              void* d_out, int out_size, void* d_ws, size_t ws_size,
                              hipStream_t stream) {
  const float* user_emb = (const float*)d_in[0];
  const float* item_emb = (const float*)d_in[1];
  const int* row = (const int*)d_in[2];
  const int* col = (const int*)d_in[3];
  // vals (d_in[4]) recomputed from degrees.

  const int NU = in_sizes[0] / 64;
  const int NI = in_sizes[1] / 64;
  const int N = NU + NI;
  const int E = in_sizes[2];
  const int Eh = E / 2;          // first half = user rows, already CSR-sorted
  const int Eh2 = E - Eh;

  float* out = (float*)d_out;

  const int K = (NI + 255) >> KB_BITS;  // item buckets of 256

  // workspace carve-up (256B-aligned blocks); 3 bf16 x-buffers kept live.
  char* p = (char*)d_ws;
  unsigned int* xb[3];
  for (int k = 0; k < 3; ++k) { xb[k] = (unsigned int*)p; p = align256(p + (size_t)N * 64 * 2); }
  int* rp = (int*)p;                   p = align256(p + (size_t)(N + 1) * 4);
  int* wgcnt = (int*)p;                p = align256(p + (size_t)K * NWG * 4);
  int* btot = (int*)p;                 p = align256(p + (size_t)K * 4);
  int* rpB = (int*)p;                  p = align256(p + (size_t)(K + 1) * 4);
  unsigned int* evcol = (unsigned int*)p;  // E * 4 bytes (only [Eh,E) used)

  const int NU16 = NU * 16;
  const int chunk = (Eh2 + NWG - 1) / NWG;
  const int BU = (Eh + BPB - 1) / BPB;

  // --- CSR build (no global atomics anywhere; separate kernels, full occupancy) ---
  rp_user_and_hist<<<BU + NWG, BPB, K * 4, stream>>>(row, rp, wgcnt, Eh, E, NU, K, chunk, BU);
  p2a_scan<<<K, TPB, 0, stream>>>(wgcnt, btot);
  p2b_scan<<<1, BPB, 0, stream>>>(btot, rpB, rp, K, Eh, E, N);
  p3_part<<<NWG, BPB, K * 4, stream>>>(row, col, wgcnt, rpB, evcol, Eh, E, NU, K, chunk);
  p4_sort<<<K, TPB, 0, stream>>>(evcol, rpB, rp, item_emb, (uint2*)xb[0], NU, NI);

  // --- scaled init, user rows only (items done in p4 tail) ---
  init_scaled<<<(NU16 + TPB - 1) / TPB, TPB, 0, stream>>>(user_emb, rp,
                                                          (uint2*)xb[0], NU16);

  // --- propagation: layers 1,2 write x~; layer 3 fused with combine ---
  const int spmm_blocks = (N * 8 + TPB - 1) / TPB;
  spmm_kernel<<<spmm_blocks, TPB, 0, stream>>>(xb[0], xb[1], rp,
                                               (const unsigned int*)col, evcol, N, NU);
  spmm_kernel<<<spmm_blocks, TPB, 0, stream>>>(xb[1], xb[2], rp,
                                               (const unsigned int*)col, evcol, N, NU);
  spmm_last_kernel<<<spmm_blocks, TPB, 0, stream>>>(xb[2], rp,
                                                    (const unsigned int*)col, evcol,
                                                    xb[1], xb[2], user_emb, item_emb,
                                                    out, N, NU);
}